// Round 19
// baseline (143.316 us; speedup 1.0000x reference)
//
#include <hip/hip_runtime.h>
#include <hip/hip_bf16.h>

#define T_DIM 2048

typedef __attribute__((ext_vector_type(8))) short short8_t;
typedef short8_t __attribute__((may_alias)) short8_a;
typedef __attribute__((ext_vector_type(4))) short short4_t;
typedef short4_t __attribute__((may_alias)) short4_a;
typedef __attribute__((ext_vector_type(4))) float f32x4;
typedef __attribute__((ext_vector_type(16))) float f32x16;
typedef __attribute__((ext_vector_type(4))) float float4_t;
typedef float4_t __attribute__((may_alias)) float4_a;
typedef __attribute__((ext_vector_type(4))) unsigned int u32x4;

__device__ __forceinline__ short f2bf(float f) {
    unsigned int u = __builtin_bit_cast(unsigned int, f);
    unsigned int r = (u + 0x7fffu + ((u >> 16) & 1u)) >> 16;
    return (short)r;
}

// async global->LDS, 16B per lane. lds dst must be wave-uniform base (+ lane*16 implicit).
__device__ __forceinline__ void gl_lds16(const short* g, short* l) {
    __builtin_amdgcn_global_load_lds(
        (const __attribute__((address_space(1))) void*)g,
        (__attribute__((address_space(3))) void*)l, 16, 0, 0);
}

// ---------------- fp32 -> bf16 cast: query + 4 weights in ONE launch ----------------
__global__ __launch_bounds__(256) void cvt_all(const float* __restrict__ query,
                                               const float* __restrict__ Wq,
                                               const float* __restrict__ Wk,
                                               const float* __restrict__ Wv,
                                               const float* __restrict__ Wo,
                                               short* __restrict__ out) {
    const int bx = blockIdx.x;
    const int i = bx * 2048 + threadIdx.x * 8;
    const float* s;
    if (bx < 2048) {
        s = query + i;
    } else {
        int j = i - 4194304;
        int wsel = j >> 20;
        const float* wp = wsel == 0 ? Wq : (wsel == 1 ? Wk : (wsel == 2 ? Wv : Wo));
        s = wp + (j & 1048575);
    }
    float4_a a = *(const float4_a*)s;
    float4_a b = *(const float4_a*)(s + 4);
    short8_a r;
    r[0] = f2bf(a[0]); r[1] = f2bf(a[1]); r[2] = f2bf(a[2]); r[3] = f2bf(a[3]);
    r[4] = f2bf(b[0]); r[5] = f2bf(b[1]); r[6] = f2bf(b[2]); r[7] = f2bf(b[3]);
    *(short8_a*)(out + i) = r;
}

// ---------------- GEMM: global_load_lds + linear LDS, BK=64 (half the barriers) -------------
// Rows are 64 shorts (128B): fragment reads are 2-way bank-aliased = free (m136).
// K out layout (proj 1): [bh][tile=t>>6][plane=d>>3][row=t&63][8]  (chunk-major for flash)
// V out layout (proj 2): [bh][tile=s>>6][plane=(s&63)>>3][row=d][8]
template <int BM, int BN, int MODE>
__global__ __launch_bounds__(256) void gemm_lds(const short* __restrict__ A,
                                                const short* __restrict__ W,
                                                const float* __restrict__ b0,
                                                const float* __restrict__ b1,
                                                const float* __restrict__ b2,
                                                short* __restrict__ o0,
                                                short* __restrict__ o1,
                                                short* __restrict__ o2,
                                                float* __restrict__ of) {
    constexpr int FM = BM / 32;
    constexpr int FN = BN / 32;
    __shared__ short As[BM * 64];
    __shared__ short Bs[BN * 64];

    const int tid = threadIdx.x;
    const int l = tid & 63, w = tid >> 6;
    const int wm = w >> 1, wn = w & 1;

    // XCD swizzle: each XCD gets a contiguous run of same-M-panel blocks (A L2-reuse)
    const int nbx = gridDim.x;
    const int nb = nbx * gridDim.y;
    const int bid = blockIdx.x + nbx * blockIdx.y;
    const int swz = (bid & 7) * (nb >> 3) + (bid >> 3);
    const int bx = swz % nbx, by = swz / nbx;

    const int m0 = by * BM, n0 = bx * BN;
    const int l15 = l & 15, l4 = l >> 4;
    const int lr = l >> 3, lc = (l & 7) * 8;  // staging lane: 8 rows x 8 chunks per inst

    f32x4 acc[FM][FN];
#pragma unroll
    for (int i = 0; i < FM; i++)
#pragma unroll
        for (int j = 0; j < FN; j++) {
            f32x4 z = {0.f, 0.f, 0.f, 0.f};
            acc[i][j] = z;
        }

    const short* Ab = A + (m0 + lr) * 1024 + lc;
    const short* Wb = W + (n0 + lr) * 1024 + lc;

    for (int k0 = 0; k0 < 1024; k0 += 64) {
        // stage: 1 KB per inst = 8 rows of 64 shorts; BM/32 insts per wave for A
#pragma unroll
        for (int j = 0; j < BM / 32; j++) {
            int base = (j * 4 + w) * 8;  // 8 rows per inst
            gl_lds16(Ab + base * 1024 + k0, &As[base * 64]);
        }
#pragma unroll
        for (int j = 0; j < BN / 32; j++) {
            int base = (j * 4 + w) * 8;
            gl_lds16(Wb + base * 1024 + k0, &Bs[base * 64]);
        }
        __syncthreads();  // drains vmcnt -> tiles staged

#pragma unroll
        for (int kk = 0; kk < 2; kk++) {
            short8_t af[FM], bf[FN];
#pragma unroll
            for (int m = 0; m < FM; m++)
                af[m] = *(const short8_a*)&As[(wm * (BM / 2) + m * 16 + l15) * 64 + kk * 32 + l4 * 8];
#pragma unroll
            for (int n = 0; n < FN; n++)
                bf[n] = *(const short8_a*)&Bs[(wn * (BN / 2) + n * 16 + l15) * 64 + kk * 32 + l4 * 8];
#pragma unroll
            for (int m = 0; m < FM; m++)
#pragma unroll
                for (int n = 0; n < FN; n++)
                    acc[m][n] = __builtin_amdgcn_mfma_f32_16x16x32_bf16(af[m], bf[n], acc[m][n], 0, 0, 0);
        }
        __syncthreads();  // readers done before next stage overwrites
    }

    if (MODE == 3) {
#pragma unroll
        for (int n = 0; n < FN; n++) {
            int col = n0 + wn * (BN / 2) + n * 16 + l15;
            float bv = b0[col];
#pragma unroll
            for (int m = 0; m < FM; m++)
#pragma unroll
                for (int i = 0; i < 4; i++) {
                    int row = m0 + wm * (BM / 2) + m * 16 + l4 * 4 + i;
                    of[row * 1024 + col] = acc[m][n][i] + bv;
                }
        }
    } else {
        const int proj = n0 >> 10;
        const float* bias = proj == 0 ? b0 : (proj == 1 ? b1 : b2);
        short* outp = proj == 0 ? o0 : (proj == 1 ? o1 : o2);
#pragma unroll
        for (int n = 0; n < FN; n++) {
            int cw = (n0 + wn * (BN / 2) + n * 16 + l15) & 1023;
            float bv = bias[cw];
            int h = cw >> 6, d = cw & 63;
#pragma unroll
            for (int m = 0; m < FM; m++)
#pragma unroll
                for (int i = 0; i < 4; i++) {
                    int row = m0 + wm * (BM / 2) + m * 16 + l4 * 4 + i;
                    float v = acc[m][n][i] + bv;
                    if (proj == 0) v *= 0.18033688011112042f;  // 0.125 * log2(e)
                    int bb = row & 1, t = row >> 1;
                    int bh = bb * 16 + h;
                    if (proj == 0)
                        outp[(bh * 2048 + t) * 64 + d] = f2bf(v);
                    else if (proj == 1)  // K chunk-major: [bh][t>>6][d>>3][t&63][d&7]
                        outp[bh * 131072 + (t >> 6) * 4096 + (d >> 3) * 512 + (t & 63) * 8 + (d & 7)] = f2bf(v);
                    else                 // V chunk-major: [bh][t>>6][(t&63)>>3][d][t&7]
                        outp[bh * 131072 + (t >> 6) * 4096 + ((t & 63) >> 3) * 512 + d * 8 + (t & 7)] = f2bf(v);
                }
        }
    }
}

// ---------------- flash attention: interleaved-KV split + chunk-major LDS (R18 champion) -------
// Wave (w4 = w>>1, g = w&1): g=0 even KV tiles, g=1 odd. Static softmax => partials ADD.
// Shared 4-slot rings (8 KB/slot); staging role-split (waves 0-3 K, 4-7 V). 64 KB LDS,
// 2 blocks/CU. No s_setprio (R18: removal was +2.7 us in this barrier-lockstep loop).
__global__ __launch_bounds__(512, 4) void flash_attn(const short* __restrict__ Q,
                                                     const short* __restrict__ K,
                                                     const short* __restrict__ Vt,
                                                     short* __restrict__ O) {
    __shared__ short Ks[4][64 * 64];  // [slot][plane=d-octet][row=s][8]  32 KB
    __shared__ short Vs[4][64 * 64];  // [slot][plane=s-octet][row=d][8]  32 KB

    const int tid = threadIdx.x, l = tid & 63, w = tid >> 6;
    const int w4 = w >> 1, g = w & 1;
    const int l31 = l & 31, hi = l >> 5;

    // T1: all 16 q-tiles of one bh on one XCD
    const int bid = blockIdx.x + (blockIdx.y << 4);
    const int swz = (bid & 7) * 64 + (bid >> 3);
    const int qt = swz & 15, bh = swz >> 4;

    const int b = bh >> 4, hh = bh & 15;
    const int qrow = qt * 128 + w4 * 32 + l31;

    const short* Qp = Q + bh * (T_DIM * 64);
    const short* Kp = K + bh * 131072;
    const short* Vp = Vt + bh * 131072;

    short8_t qf[4];
#pragma unroll
    for (int c = 0; c < 4; c++)
        qf[c] = *(const short8_a*)&Qp[qrow * 64 + c * 16 + hi * 8];

    f32x16 oacc[2];
    f32x16 lacc;  // row-sum via ones-MFMA; only [0] consumed
#pragma unroll
    for (int i = 0; i < 16; i++) { oacc[0][i] = 0.f; oacc[1][i] = 0.f; lacc[i] = 0.f; }

    short8_t ones;
#pragma unroll
    for (int j = 0; j < 8; j++) ones[j] = (short)0x3F80;  // bf16 1.0

    // staging: per tile = 8 planes x 1KB; waves 0-3 stage K planes {2wq,2wq+1}, 4-7 V.
    const int wq = w & 3;
    const int p0 = 2 * wq, p1 = 2 * wq + 1;
    const short* sgK0 = Kp + p0 * 512 + l * 8;
    const short* sgK1 = Kp + p1 * 512 + l * 8;
    const short* sgV0 = Vp + p0 * 512 + l * 8;
    const short* sgV1 = Vp + p1 * 512 + l * 8;

    auto stage = [&](int t) {
        const int buf = t & 3, off = t * 4096;
        if (w < 4) {
            gl_lds16(sgK0 + off, &Ks[buf][p0 * 512]);
            gl_lds16(sgK1 + off, &Ks[buf][p1 * 512]);
        } else {
            gl_lds16(sgV0 + off, &Vs[buf][p0 * 512]);
            gl_lds16(sgV1 + off, &Vs[buf][p1 * 512]);
        }
    };

    // QK half r: S^T[k = r*32..r*32+31][q = l31] -> 16 scores per lane
    auto qkhalf = [&](f32x16& s, int t, int r) {
        const short* kc = &Ks[t & 3][0];
#pragma unroll
        for (int c = 0; c < 4; c++) {
            short8_t kf = *(const short8_a*)&kc[(2 * c + hi) * 512 + (r * 32 + l31) * 8];
            if (c == 0) {
                f32x16 z;
#pragma unroll
                for (int i = 0; i < 16; i++) z[i] = 0.f;
                s = __builtin_amdgcn_mfma_f32_32x32x16_bf16(kf, qf[0], z, 0, 0, 0);
            } else {
                s = __builtin_amdgcn_mfma_f32_32x32x16_bf16(kf, qf[c], s, 0, 0, 0);
            }
        }
    };

    // static softmax: P = exp2(s); pack 16 scores -> 2 PV B-frags
    auto expackhalf = [&](f32x16& s, short8_t* pf2) {
#pragma unroll
        for (int i = 0; i < 16; i++) s[i] = exp2f(s[i]);
        unsigned pk8[8];
#pragma unroll
        for (int u = 0; u < 8; u++) {
            unsigned t;
            asm("v_cvt_pk_bf16_f32 %0, %1, %2" : "=v"(t) : "v"(s[2 * u]), "v"(s[2 * u + 1]));
            pk8[u] = t;
        }
#pragma unroll
        for (int cc = 0; cc < 2; cc++) {
            unsigned A0 = pk8[4 * cc + 0], B0 = pk8[4 * cc + 2];
            unsigned A1 = pk8[4 * cc + 1], B1 = pk8[4 * cc + 3];
            asm("v_permlane32_swap_b32 %0, %1" : "+v"(A0), "+v"(B0));
            asm("v_permlane32_swap_b32 %0, %1" : "+v"(A1), "+v"(B1));
            u32x4 pu = {A0, A1, B0, B1};
            pf2[cc] = __builtin_bit_cast(short8_t, pu);
        }
    };

    auto pv = [&](const short8_t* pf, int t) {
        const short* vc = &Vs[t & 3][0];
#pragma unroll
        for (int r = 0; r < 2; r++)
#pragma unroll
            for (int cc = 0; cc < 2; cc++) {
                short8_t p = pf[r * 2 + cc];
#pragma unroll
                for (int dd = 0; dd < 2; dd++) {
                    short8_t vf = *(const short8_a*)&vc[(4 * r + 2 * cc + hi) * 512 +
                                                        (dd * 32 + l31) * 8];
                    oacc[dd] = __builtin_amdgcn_mfma_f32_32x32x16_bf16(vf, p, oacc[dd], 0, 0, 0);
                }
                lacc = __builtin_amdgcn_mfma_f32_32x32x16_bf16(ones, p, lacc, 0, 0, 0);
            }
    };

    // prologue: tiles 0,1
    stage(0);
    stage(1);

    f32x16 s;
    short8_t pf[4];

    for (int p = 0; p < 16; ++p) {
        __syncthreads();  // phase p-1's stages landed; phase p-1's reads done
        if (p < 15) { stage(2 * p + 2); stage(2 * p + 3); }
        const int t = 2 * p + g;
        qkhalf(s, t, 0);
        expackhalf(s, &pf[0]);
        qkhalf(s, t, 1);
        expackhalf(s, &pf[2]);
        pv(pf, t);
    }

    // ---- combine g=0 + g=1 partials (pure addition -- static softmax) ----
    __syncthreads();
    float* xo = (float*)&Ks[0][0];   // 8192 f32 = 32 KB: 4 pairs x 2048
    float* xml = (float*)&Vs[0][0];  // 4 pairs x 64
    if (g == 1) {
#pragma unroll
        for (int dd = 0; dd < 2; dd++)
#pragma unroll
            for (int g4 = 0; g4 < 4; g4++) {
                f32x4 v = {oacc[dd][4 * g4], oacc[dd][4 * g4 + 1],
                           oacc[dd][4 * g4 + 2], oacc[dd][4 * g4 + 3]};
                *(float4_a*)&xo[w4 * 2048 + (dd * 4 + g4) * 256 + l * 4] = v;
            }
        xml[w4 * 64 + l] = lacc[0];
    }
    __syncthreads();
    if (g == 0) {
        float rl = 1.0f / (lacc[0] + xml[w4 * 64 + l]);
        // lane holds O^T[d][q=l31], d = (reg&3)+8*(reg>>2)+4*hi+32*dd
#pragma unroll
        for (int dd = 0; dd < 2; dd++)
#pragma unroll
            for (int g4 = 0; g4 < 4; g4++) {
                f32x4 o1 = *(const float4_a*)&xo[w4 * 2048 + (dd * 4 + g4) * 256 + l * 4];
                short4_t o4;
#pragma unroll
                for (int i = 0; i < 4; i++)
                    o4[i] = f2bf((oacc[dd][4 * g4 + i] + o1[i]) * rl);
                *(short4_a*)&O[(qrow * 2 + b) * 1024 + hh * 64 + dd * 32 + g4 * 8 + hi * 4] = o4;
            }
    }
}

extern "C" void kernel_launch(void* const* d_in, const int* in_sizes, int n_in,
                              void* d_out, int out_size, void* d_ws, size_t ws_size,
                              hipStream_t stream) {
    const float* query = (const float*)d_in[0];
    const float* Wq = (const float*)d_in[1];
    const float* bq = (const float*)d_in[2];
    const float* Wk = (const float*)d_in[3];
    const float* bk = (const float*)d_in[4];
    const float* Wv = (const float*)d_in[5];
    const float* bv = (const float*)d_in[6];
    const float* Wo = (const float*)d_in[7];
    const float* bo = (const float*)d_in[8];

    short* Xbf = (short*)d_ws;        // 4096x1024 bf16 query (8 MB) -- reused as attn out
    short* Wqb = Xbf + 4194304;       // Wq|Wk|Wv contiguous = fused [3072][1024]
    short* Wkb = Wqb + 1048576;
    short* Wvb = Wkb + 1048576;
    short* Wob = Wvb + 1048576;
    short* Qb = Wob + 1048576;        // [B,H,T,D] 8 MB
    short* Kb = Qb + 4194304;        // chunk-major [bh][tile][plane][row][8] 8 MB
    short* Vtb = Kb + 4194304;       // chunk-major 8 MB
    short* attnb = Xbf;

    cvt_all<<<4096, 256, 0, stream>>>(query, Wq, Wk, Wv, Wo, Xbf);

    gemm_lds<128, 128, 4><<<dim3(24, 32), 256, 0, stream>>>(Xbf, Wqb, bq, bk, bv,
                                                            Qb, Kb, Vtb, nullptr);

    // flash: 512 threads (8 waves, interleaved-KV split), 512 blocks, 64 KB LDS
    flash_attn<<<dim3(16, 32), 512, 0, stream>>>(Qb, Kb, Vtb, attnb);

    gemm_lds<64, 128, 3><<<dim3(8, 64), 256, 0, stream>>>(attnb, Wob, bo, nullptr, nullptr,
                                                          nullptr, nullptr, nullptr, (float*)d_out);
}

// Round 20
// 114.455 us; speedup vs baseline: 1.2522x; 1.2522x over previous
//
#include <hip/hip_runtime.h>
#include <hip/hip_bf16.h>

#define T_DIM 2048

typedef __attribute__((ext_vector_type(8))) short short8_t;
typedef short8_t __attribute__((may_alias)) short8_a;
typedef __attribute__((ext_vector_type(4))) short short4_t;
typedef short4_t __attribute__((may_alias)) short4_a;
typedef __attribute__((ext_vector_type(4))) float f32x4;
typedef __attribute__((ext_vector_type(16))) float f32x16;
typedef __attribute__((ext_vector_type(4))) float float4_t;
typedef float4_t __attribute__((may_alias)) float4_a;
typedef __attribute__((ext_vector_type(4))) unsigned int u32x4;

__device__ __forceinline__ short f2bf(float f) {
    unsigned int u = __builtin_bit_cast(unsigned int, f);
    unsigned int r = (u + 0x7fffu + ((u >> 16) & 1u)) >> 16;
    return (short)r;
}

// async global->LDS, 16B per lane. lds dst must be wave-uniform base (+ lane*16 implicit).
__device__ __forceinline__ void gl_lds16(const short* g, short* l) {
    __builtin_amdgcn_global_load_lds(
        (const __attribute__((address_space(1))) void*)g,
        (__attribute__((address_space(3))) void*)l, 16, 0, 0);
}

// ---------------- fp32 -> bf16 cast: query + 4 weights in ONE launch ----------------
__global__ __launch_bounds__(256) void cvt_all(const float* __restrict__ query,
                                               const float* __restrict__ Wq,
                                               const float* __restrict__ Wk,
                                               const float* __restrict__ Wv,
                                               const float* __restrict__ Wo,
                                               short* __restrict__ out) {
    const int bx = blockIdx.x;
    const int i = bx * 2048 + threadIdx.x * 8;
    const float* s;
    if (bx < 2048) {
        s = query + i;
    } else {
        int j = i - 4194304;
        int wsel = j >> 20;
        const float* wp = wsel == 0 ? Wq : (wsel == 1 ? Wk : (wsel == 2 ? Wv : Wo));
        s = wp + (j & 1048575);
    }
    float4_a a = *(const float4_a*)s;
    float4_a b = *(const float4_a*)(s + 4);
    short8_a r;
    r[0] = f2bf(a[0]); r[1] = f2bf(a[1]); r[2] = f2bf(a[2]); r[3] = f2bf(a[3]);
    r[4] = f2bf(b[0]); r[5] = f2bf(b[1]); r[6] = f2bf(b[2]); r[7] = f2bf(b[3]);
    *(short8_a*)(out + i) = r;
}

// ---------------- GEMM: BK=64 + XOR-swizzled chunk slots (conflict-free 128B rows) ----------
// LDS row = 64 shorts; chunk c of row r stored at slot c^(r&7) via PRE-SWIZZLED gl_lds
// source (LDS write linear, rule #21). Fragment reads use the same XOR -> 2-way aliasing
// (free, m136). Half the barriers of BK=32 (32 per block at K=1024).
// K out layout (proj 1): [bh][tile=t>>6][plane=d>>3][row=t&63][8]  (chunk-major for flash)
// V out layout (proj 2): [bh][tile=s>>6][plane=(s&63)>>3][row=d][8]
template <int BM, int BN, int MODE>
__global__ __launch_bounds__(256) void gemm_lds(const short* __restrict__ A,
                                                const short* __restrict__ W,
                                                const float* __restrict__ b0,
                                                const float* __restrict__ b1,
                                                const float* __restrict__ b2,
                                                short* __restrict__ o0,
                                                short* __restrict__ o1,
                                                short* __restrict__ o2,
                                                float* __restrict__ of) {
    constexpr int FM = BM / 32;
    constexpr int FN = BN / 32;
    __shared__ short As[BM * 64];
    __shared__ short Bs[BN * 64];

    const int tid = threadIdx.x;
    const int l = tid & 63, w = tid >> 6;
    const int wm = w >> 1, wn = w & 1;

    // XCD swizzle: each XCD gets a contiguous run of same-M-panel blocks (A L2-reuse)
    const int nbx = gridDim.x;
    const int nb = nbx * gridDim.y;
    const int bid = blockIdx.x + nbx * blockIdx.y;
    const int swz = (bid & 7) * (nb >> 3) + (bid >> 3);
    const int bx = swz % nbx, by = swz / nbx;

    const int m0 = by * BM, n0 = bx * BN;
    const int l15 = l & 15, l4 = l >> 4;
    const int e7 = l15 & 7;  // row&7 for fragment reads
    // staging lane: 8 rows x 8 chunks per inst; source chunk pre-swizzled by row&7
    const int lr = l >> 3;
    const int lc = ((l & 7) ^ (lr & 7)) * 8;

    f32x4 acc[FM][FN];
#pragma unroll
    for (int i = 0; i < FM; i++)
#pragma unroll
        for (int j = 0; j < FN; j++) {
            f32x4 z = {0.f, 0.f, 0.f, 0.f};
            acc[i][j] = z;
        }

    const short* Ab = A + (m0 + lr) * 1024 + lc;
    const short* Wb = W + (n0 + lr) * 1024 + lc;

    for (int k0 = 0; k0 < 1024; k0 += 64) {
        // stage: 1 KB per inst = 8 rows of 64 shorts; linear LDS dest, swizzled source
#pragma unroll
        for (int j = 0; j < BM / 32; j++) {
            int base = (j * 4 + w) * 8;  // 8 rows per inst
            gl_lds16(Ab + base * 1024 + k0, &As[base * 64]);
        }
#pragma unroll
        for (int j = 0; j < BN / 32; j++) {
            int base = (j * 4 + w) * 8;
            gl_lds16(Wb + base * 1024 + k0, &Bs[base * 64]);
        }
        __syncthreads();  // drains vmcnt -> tiles staged

#pragma unroll
        for (int kk = 0; kk < 2; kk++) {
            short8_t af[FM], bf[FN];
#pragma unroll
            for (int m = 0; m < FM; m++)
                af[m] = *(const short8_a*)&As[(wm * (BM / 2) + m * 16 + l15) * 64 +
                                              ((kk * 4 + l4) ^ e7) * 8];
#pragma unroll
            for (int n = 0; n < FN; n++)
                bf[n] = *(const short8_a*)&Bs[(wn * (BN / 2) + n * 16 + l15) * 64 +
                                              ((kk * 4 + l4) ^ e7) * 8];
#pragma unroll
            for (int m = 0; m < FM; m++)
#pragma unroll
                for (int n = 0; n < FN; n++)
                    acc[m][n] = __builtin_amdgcn_mfma_f32_16x16x32_bf16(af[m], bf[n], acc[m][n], 0, 0, 0);
        }
        __syncthreads();  // readers done before next stage overwrites
    }

    if (MODE == 3) {
#pragma unroll
        for (int n = 0; n < FN; n++) {
            int col = n0 + wn * (BN / 2) + n * 16 + l15;
            float bv = b0[col];
#pragma unroll
            for (int m = 0; m < FM; m++)
#pragma unroll
                for (int i = 0; i < 4; i++) {
                    int row = m0 + wm * (BM / 2) + m * 16 + (l >> 4) * 4 + i;
                    of[row * 1024 + col] = acc[m][n][i] + bv;
                }
        }
    } else {
        const int proj = n0 >> 10;
        const float* bias = proj == 0 ? b0 : (proj == 1 ? b1 : b2);
        short* outp = proj == 0 ? o0 : (proj == 1 ? o1 : o2);
#pragma unroll
        for (int n = 0; n < FN; n++) {
            int cw = (n0 + wn * (BN / 2) + n * 16 + l15) & 1023;
            float bv = bias[cw];
            int h = cw >> 6, d = cw & 63;
#pragma unroll
            for (int m = 0; m < FM; m++)
#pragma unroll
                for (int i = 0; i < 4; i++) {
                    int row = m0 + wm * (BM / 2) + m * 16 + (l >> 4) * 4 + i;
                    float v = acc[m][n][i] + bv;
                    if (proj == 0) v *= 0.18033688011112042f;  // 0.125 * log2(e)
                    int bb = row & 1, t = row >> 1;
                    int bh = bb * 16 + h;
                    if (proj == 0)
                        outp[(bh * 2048 + t) * 64 + d] = f2bf(v);
                    else if (proj == 1)  // K chunk-major: [bh][t>>6][d>>3][t&63][d&7]
                        outp[bh * 131072 + (t >> 6) * 4096 + (d >> 3) * 512 + (t & 63) * 8 + (d & 7)] = f2bf(v);
                    else                 // V chunk-major: [bh][t>>6][(t&63)>>3][d][t&7]
                        outp[bh * 131072 + (t >> 6) * 4096 + ((t & 63) >> 3) * 512 + d * 8 + (t & 7)] = f2bf(v);
                }
        }
    }
}

// ---------------- flash attention: interleaved-KV split + chunk-major LDS (R18 champion) -------
// Wave (w4 = w>>1, g = w&1): g=0 even KV tiles, g=1 odd. Static softmax => partials ADD.
// Shared 4-slot rings (8 KB/slot); staging role-split (waves 0-3 K, 4-7 V). 64 KB LDS,
// 2 blocks/CU. No s_setprio (R18: removal was +2.7 us in this barrier-lockstep loop).
__global__ __launch_bounds__(512, 4) void flash_attn(const short* __restrict__ Q,
                                                     const short* __restrict__ K,
                                                     const short* __restrict__ Vt,
                                                     short* __restrict__ O) {
    __shared__ short Ks[4][64 * 64];  // [slot][plane=d-octet][row=s][8]  32 KB
    __shared__ short Vs[4][64 * 64];  // [slot][plane=s-octet][row=d][8]  32 KB

    const int tid = threadIdx.x, l = tid & 63, w = tid >> 6;
    const int w4 = w >> 1, g = w & 1;
    const int l31 = l & 31, hi = l >> 5;

    // T1: all 16 q-tiles of one bh on one XCD
    const int bid = blockIdx.x + (blockIdx.y << 4);
    const int swz = (bid & 7) * 64 + (bid >> 3);
    const int qt = swz & 15, bh = swz >> 4;

    const int b = bh >> 4, hh = bh & 15;
    const int qrow = qt * 128 + w4 * 32 + l31;

    const short* Qp = Q + bh * (T_DIM * 64);
    const short* Kp = K + bh * 131072;
    const short* Vp = Vt + bh * 131072;

    short8_t qf[4];
#pragma unroll
    for (int c = 0; c < 4; c++)
        qf[c] = *(const short8_a*)&Qp[qrow * 64 + c * 16 + hi * 8];

    f32x16 oacc[2];
    f32x16 lacc;  // row-sum via ones-MFMA; only [0] consumed
#pragma unroll
    for (int i = 0; i < 16; i++) { oacc[0][i] = 0.f; oacc[1][i] = 0.f; lacc[i] = 0.f; }

    short8_t ones;
#pragma unroll
    for (int j = 0; j < 8; j++) ones[j] = (short)0x3F80;  // bf16 1.0

    // staging: per tile = 8 planes x 1KB; waves 0-3 stage K planes {2wq,2wq+1}, 4-7 V.
    const int wq = w & 3;
    const int p0 = 2 * wq, p1 = 2 * wq + 1;
    const short* sgK0 = Kp + p0 * 512 + l * 8;
    const short* sgK1 = Kp + p1 * 512 + l * 8;
    const short* sgV0 = Vp + p0 * 512 + l * 8;
    const short* sgV1 = Vp + p1 * 512 + l * 8;

    auto stage = [&](int t) {
        const int buf = t & 3, off = t * 4096;
        if (w < 4) {
            gl_lds16(sgK0 + off, &Ks[buf][p0 * 512]);
            gl_lds16(sgK1 + off, &Ks[buf][p1 * 512]);
        } else {
            gl_lds16(sgV0 + off, &Vs[buf][p0 * 512]);
            gl_lds16(sgV1 + off, &Vs[buf][p1 * 512]);
        }
    };

    // QK half r: S^T[k = r*32..r*32+31][q = l31] -> 16 scores per lane
    auto qkhalf = [&](f32x16& s, int t, int r) {
        const short* kc = &Ks[t & 3][0];
#pragma unroll
        for (int c = 0; c < 4; c++) {
            short8_t kf = *(const short8_a*)&kc[(2 * c + hi) * 512 + (r * 32 + l31) * 8];
            if (c == 0) {
                f32x16 z;
#pragma unroll
                for (int i = 0; i < 16; i++) z[i] = 0.f;
                s = __builtin_amdgcn_mfma_f32_32x32x16_bf16(kf, qf[0], z, 0, 0, 0);
            } else {
                s = __builtin_amdgcn_mfma_f32_32x32x16_bf16(kf, qf[c], s, 0, 0, 0);
            }
        }
    };

    // static softmax: P = exp2(s); pack 16 scores -> 2 PV B-frags
    auto expackhalf = [&](f32x16& s, short8_t* pf2) {
#pragma unroll
        for (int i = 0; i < 16; i++) s[i] = exp2f(s[i]);
        unsigned pk8[8];
#pragma unroll
        for (int u = 0; u < 8; u++) {
            unsigned t;
            asm("v_cvt_pk_bf16_f32 %0, %1, %2" : "=v"(t) : "v"(s[2 * u]), "v"(s[2 * u + 1]));
            pk8[u] = t;
        }
#pragma unroll
        for (int cc = 0; cc < 2; cc++) {
            unsigned A0 = pk8[4 * cc + 0], B0 = pk8[4 * cc + 2];
            unsigned A1 = pk8[4 * cc + 1], B1 = pk8[4 * cc + 3];
            asm("v_permlane32_swap_b32 %0, %1" : "+v"(A0), "+v"(B0));
            asm("v_permlane32_swap_b32 %0, %1" : "+v"(A1), "+v"(B1));
            u32x4 pu = {A0, A1, B0, B1};
            pf2[cc] = __builtin_bit_cast(short8_t, pu);
        }
    };

    auto pv = [&](const short8_t* pf, int t) {
        const short* vc = &Vs[t & 3][0];
#pragma unroll
        for (int r = 0; r < 2; r++)
#pragma unroll
            for (int cc = 0; cc < 2; cc++) {
                short8_t p = pf[r * 2 + cc];
#pragma unroll
                for (int dd = 0; dd < 2; dd++) {
                    short8_t vf = *(const short8_a*)&vc[(4 * r + 2 * cc + hi) * 512 +
                                                        (dd * 32 + l31) * 8];
                    oacc[dd] = __builtin_amdgcn_mfma_f32_32x32x16_bf16(vf, p, oacc[dd], 0, 0, 0);
                }
                lacc = __builtin_amdgcn_mfma_f32_32x32x16_bf16(ones, p, lacc, 0, 0, 0);
            }
    };

    // prologue: tiles 0,1
    stage(0);
    stage(1);

    f32x16 s;
    short8_t pf[4];

    for (int p = 0; p < 16; ++p) {
        __syncthreads();  // phase p-1's stages landed; phase p-1's reads done
        if (p < 15) { stage(2 * p + 2); stage(2 * p + 3); }
        const int t = 2 * p + g;
        qkhalf(s, t, 0);
        expackhalf(s, &pf[0]);
        qkhalf(s, t, 1);
        expackhalf(s, &pf[2]);
        pv(pf, t);
    }

    // ---- combine g=0 + g=1 partials (pure addition -- static softmax) ----
    __syncthreads();
    float* xo = (float*)&Ks[0][0];   // 8192 f32 = 32 KB: 4 pairs x 2048
    float* xml = (float*)&Vs[0][0];  // 4 pairs x 64
    if (g == 1) {
#pragma unroll
        for (int dd = 0; dd < 2; dd++)
#pragma unroll
            for (int g4 = 0; g4 < 4; g4++) {
                f32x4 v = {oacc[dd][4 * g4], oacc[dd][4 * g4 + 1],
                           oacc[dd][4 * g4 + 2], oacc[dd][4 * g4 + 3]};
                *(float4_a*)&xo[w4 * 2048 + (dd * 4 + g4) * 256 + l * 4] = v;
            }
        xml[w4 * 64 + l] = lacc[0];
    }
    __syncthreads();
    if (g == 0) {
        float rl = 1.0f / (lacc[0] + xml[w4 * 64 + l]);
        // lane holds O^T[d][q=l31], d = (reg&3)+8*(reg>>2)+4*hi+32*dd
#pragma unroll
        for (int dd = 0; dd < 2; dd++)
#pragma unroll
            for (int g4 = 0; g4 < 4; g4++) {
                f32x4 o1 = *(const float4_a*)&xo[w4 * 2048 + (dd * 4 + g4) * 256 + l * 4];
                short4_t o4;
#pragma unroll
                for (int i = 0; i < 4; i++)
                    o4[i] = f2bf((oacc[dd][4 * g4 + i] + o1[i]) * rl);
                *(short4_a*)&O[(qrow * 2 + b) * 1024 + hh * 64 + dd * 32 + g4 * 8 + hi * 4] = o4;
            }
    }
}

extern "C" void kernel_launch(void* const* d_in, const int* in_sizes, int n_in,
                              void* d_out, int out_size, void* d_ws, size_t ws_size,
                              hipStream_t stream) {
    const float* query = (const float*)d_in[0];
    const float* Wq = (const float*)d_in[1];
    const float* bq = (const float*)d_in[2];
    const float* Wk = (const float*)d_in[3];
    const float* bk = (const float*)d_in[4];
    const float* Wv = (const float*)d_in[5];
    const float* bv = (const float*)d_in[6];
    const float* Wo = (const float*)d_in[7];
    const float* bo = (const float*)d_in[8];

    short* Xbf = (short*)d_ws;        // 4096x1024 bf16 query (8 MB) -- reused as attn out
    short* Wqb = Xbf + 4194304;       // Wq|Wk|Wv contiguous = fused [3072][1024]
    short* Wkb = Wqb + 1048576;
    short* Wvb = Wkb + 1048576;
    short* Wob = Wvb + 1048576;
    short* Qb = Wob + 1048576;        // [B,H,T,D] 8 MB
    short* Kb = Qb + 4194304;        // chunk-major [bh][tile][plane][row][8] 8 MB
    short* Vtb = Kb + 4194304;       // chunk-major 8 MB
    short* attnb = Xbf;

    cvt_all<<<4096, 256, 0, stream>>>(query, Wq, Wk, Wv, Wo, Xbf);

    gemm_lds<128, 128, 4><<<dim3(24, 32), 256, 0, stream>>>(Xbf, Wqb, bq, bk, bv,
                                                            Qb, Kb, Vtb, nullptr);

    // flash: 512 threads (8 waves, interleaved-KV split), 512 blocks, 64 KB LDS
    flash_attn<<<dim3(16, 32), 512, 0, stream>>>(Qb, Kb, Vtb, attnb);

    gemm_lds<64, 128, 3><<<dim3(8, 64), 256, 0, stream>>>(attnb, Wob, bo, nullptr, nullptr,
                                                          nullptr, nullptr, nullptr, (float*)d_out);
}